// Round 1
// baseline (2603.198 us; speedup 1.0000x reference)
//
#include <hip/hip_runtime.h>
#include <cstdint>
#include <cstddef>

#define NFEAT 512
#define NHID1 256
#define NHID2 64
#define ATTH  16

enum { EPI_NONE=0, EPI_RELU=1, EPI_BNRELU=2, EPI_SIGMOID=3, EPI_SOFTPLUS=4, EPI_EXPCLIP=5 };

// ---------------- fp32 tiled GEMM: C = epi(A[M,K] @ B[K,Nn] + bias) ----------------
// 64x64 C-tile, 256 threads, 4x4 per thread, K-tile 16. A stored transposed in LDS
// so both fragment reads are contiguous (ds_read_b128).
template<int EPI>
__global__ __launch_bounds__(256) void gemm_kernel(
    const float* __restrict__ A, const float* __restrict__ B,
    const float* __restrict__ bias, float* __restrict__ C,
    int M, int K, int Nn,
    const float* __restrict__ bn_g, const float* __restrict__ bn_b,
    const float* __restrict__ bn_m, const float* __restrict__ bn_v)
{
    __shared__ float As[16][65];   // [k][row]
    __shared__ float Bs[16][68];   // [k][col]
    const int t  = threadIdx.x;
    const int tx = t & 15, ty = t >> 4;
    const int rowBase = blockIdx.y * 64, colBase = blockIdx.x * 64;
    const int arow = t >> 2, ak = (t & 3) * 4;   // A loader: row 0..63, k 0..12
    const int brow = t >> 4, bc = (t & 15) * 4;  // B loader: k 0..15, col 0..60

    float acc[4][4];
    #pragma unroll
    for (int i = 0; i < 4; ++i)
        #pragma unroll
        for (int j = 0; j < 4; ++j) acc[i][j] = 0.f;

    for (int k0 = 0; k0 < K; k0 += 16) {
        float4 av = make_float4(0.f, 0.f, 0.f, 0.f);
        int gr = rowBase + arow;
        if (gr < M) av = *reinterpret_cast<const float4*>(A + (size_t)gr * K + k0 + ak);
        float4 bv = *reinterpret_cast<const float4*>(B + (size_t)(k0 + brow) * Nn + colBase + bc);
        As[ak+0][arow] = av.x; As[ak+1][arow] = av.y;
        As[ak+2][arow] = av.z; As[ak+3][arow] = av.w;
        Bs[brow][bc+0] = bv.x; Bs[brow][bc+1] = bv.y;
        Bs[brow][bc+2] = bv.z; Bs[brow][bc+3] = bv.w;
        __syncthreads();
        #pragma unroll
        for (int kk = 0; kk < 16; ++kk) {
            float a[4], b[4];
            #pragma unroll
            for (int i = 0; i < 4; ++i) a[i] = As[kk][ty*4 + i];
            #pragma unroll
            for (int j = 0; j < 4; ++j) b[j] = Bs[kk][tx*4 + j];
            #pragma unroll
            for (int i = 0; i < 4; ++i)
                #pragma unroll
                for (int j = 0; j < 4; ++j) acc[i][j] = fmaf(a[i], b[j], acc[i][j]);
        }
        __syncthreads();
    }

    #pragma unroll
    for (int i = 0; i < 4; ++i) {
        int r = rowBase + ty*4 + i;
        if (r >= M) continue;
        #pragma unroll
        for (int j = 0; j < 4; ++j) {
            int c = colBase + tx*4 + j;
            float v = acc[i][j];
            if (bias) v += bias[c];
            if (EPI == EPI_RELU) {
                v = fmaxf(v, 0.f);
            } else if (EPI == EPI_BNRELU) {
                v = (v - bn_m[c]) * rsqrtf(bn_v[c] + 1e-5f) * bn_g[c] + bn_b[c];
                v = fmaxf(v, 0.f);
            } else if (EPI == EPI_SIGMOID) {
                v = 1.f / (1.f + expf(-v));
            } else if (EPI == EPI_SOFTPLUS) {
                float sp = (v > 20.f) ? v : log1pf(expf(v));
                v = fminf(fmaxf(sp, 1e-4f), 1e4f);
            } else if (EPI == EPI_EXPCLIP) {
                v = fminf(fmaxf(expf(v), 1e-5f), 1e6f);
            }
            C[(size_t)r * Nn + c] = v;
        }
    }
}

// ---------------- CSR build ----------------
__global__ void hist_kernel(const int* __restrict__ dst, int* __restrict__ deg, int e) {
    int i = blockIdx.x * blockDim.x + threadIdx.x;
    if (i < e) atomicAdd(&deg[dst[i]], 1);
}

__global__ __launch_bounds__(1024) void scan_kernel(const int* __restrict__ deg,
                                                    int* __restrict__ row_start,
                                                    int* __restrict__ cursor, int n) {
    __shared__ int buf[1024];
    __shared__ int carry_s;
    if (threadIdx.x == 0) carry_s = 0;
    __syncthreads();
    for (int base = 0; base < n; base += 1024) {
        int i = base + (int)threadIdx.x;
        int v = (i < n) ? deg[i] : 0;
        buf[threadIdx.x] = v;
        __syncthreads();
        for (int off = 1; off < 1024; off <<= 1) {
            int tv = (threadIdx.x >= (unsigned)off) ? buf[threadIdx.x - off] : 0;
            __syncthreads();
            buf[threadIdx.x] += tv;
            __syncthreads();
        }
        int carry = carry_s;
        int inc = buf[threadIdx.x];
        if (i < n) {
            int start = carry + inc - v;
            row_start[i] = start;
            cursor[i] = start;
            if (i == n - 1) row_start[n] = carry + inc;
        }
        __syncthreads();
        if (threadIdx.x == 1023) carry_s = carry + buf[1023];
        __syncthreads();
    }
}

__global__ void scatter_kernel(const int* __restrict__ src, const int* __restrict__ dst,
                               int* __restrict__ cursor, int* __restrict__ csr_src, int e) {
    int i = blockIdx.x * blockDim.x + threadIdx.x;
    if (i < e) {
        int pos = atomicAdd(&cursor[dst[i]], 1);
        csr_src[pos] = src[i];
    }
}

// ---------------- gather aggregation + self + bias + relu ----------------
// out[n,:] = relu(xw[n,:] + sum_{s in inNbrs(n)} xw[s,:] + bias)
template<int F, int COLS>
__global__ __launch_bounds__(256) void agg_combine_kernel(
    const float* __restrict__ xw, const int* __restrict__ row_start,
    const int* __restrict__ csr_src, const float* __restrict__ bias,
    float* __restrict__ out, int n)
{
    int wave = blockIdx.x * (blockDim.x >> 6) + (threadIdx.x >> 6);
    int lane = threadIdx.x & 63;
    if (wave >= n) return;
    int beg = row_start[wave], end = row_start[wave + 1];
    float acc[COLS];
    #pragma unroll
    for (int i = 0; i < COLS; ++i) acc[i] = 0.f;
    for (int e = beg; e < end; ++e) {
        int s = csr_src[e];
        const float* row = xw + (size_t)s * F;
        #pragma unroll
        for (int i = 0; i < COLS; ++i) acc[i] += row[lane + 64*i];
    }
    const float* self = xw + (size_t)wave * F;
    #pragma unroll
    for (int i = 0; i < COLS; ++i) {
        int c = lane + 64*i;
        float v = self[c] + acc[i] + bias[c];
        out[(size_t)wave * F + c] = fmaxf(v, 0.f);
    }
}

// ---------------- fused spatial attention + mlp ----------------
__global__ __launch_bounds__(256) void attn_mlp_kernel(
    const float* __restrict__ emb1, const float* __restrict__ emb2,
    const float* __restrict__ Wa1, const float* __restrict__ ba1,
    const float* __restrict__ Wa2, const float* __restrict__ Wmlp,
    const float* __restrict__ bmlp, float* __restrict__ out, int n)
{
    __shared__ float sWa1[NHID2][ATTH];
    __shared__ float sba1[ATTH], sWa2[ATTH];
    __shared__ float sWmlp[NHID2][NHID2 + 1];
    __shared__ float sbmlp[NHID2];
    __shared__ float zs[4][3][NHID2];
    __shared__ float part[4][3][ATTH];
    __shared__ float sbeta[4][3];
    __shared__ float es[4][NHID2];

    int t = threadIdx.x;
    for (int idx = t; idx < NHID2 * ATTH; idx += 256) sWa1[idx / ATTH][idx % ATTH] = Wa1[idx];
    if (t < ATTH) { sba1[t] = ba1[t]; sWa2[t] = Wa2[t]; }
    for (int idx = t; idx < NHID2 * NHID2; idx += 256) sWmlp[idx / NHID2][idx % NHID2] = Wmlp[idx];
    if (t < NHID2) sbmlp[t] = bmlp[t];

    int w = t >> 6, lane = t & 63;
    int node = blockIdx.x * 4 + w;
    float z0 = 0.f, z2 = 0.f;
    if (node < n) {
        z0 = emb1[(size_t)node * NHID2 + lane];
        z2 = emb2[(size_t)node * NHID2 + lane];
    }
    zs[w][0][lane] = z0;
    zs[w][1][lane] = 0.5f * (z0 + z2);
    zs[w][2][lane] = z2;
    __syncthreads();

    if (t < 192) {
        int ww = t / 48, k = (t / 16) % 3, h = t % 16;
        float p = 0.f;
        #pragma unroll 8
        for (int i = 0; i < NHID2; ++i) p += zs[ww][k][i] * sWa1[i][h];
        part[ww][k][h] = tanhf(p + sba1[h]) * sWa2[h];
    }
    __syncthreads();
    if (t < 12) {
        int ww = t / 3, k = t % 3;
        float s = 0.f;
        #pragma unroll
        for (int h = 0; h < ATTH; ++h) s += part[ww][k][h];
        part[ww][k][0] = s;
    }
    __syncthreads();
    if (t < 4) {
        float w0 = part[t][0][0], w1 = part[t][1][0], w2 = part[t][2][0];
        float m = fmaxf(w0, fmaxf(w1, w2));
        float e0 = expf(w0 - m), e1 = expf(w1 - m), e2 = expf(w2 - m);
        float d = e0 + e1 + e2;
        sbeta[t][0] = e0 / d; sbeta[t][1] = e1 / d; sbeta[t][2] = e2 / d;
    }
    __syncthreads();
    es[w][lane] = sbeta[w][0] * zs[w][0][lane] + sbeta[w][1] * zs[w][1][lane]
                + sbeta[w][2] * zs[w][2][lane];
    __syncthreads();
    if (node < n) {
        float v = sbmlp[lane];
        #pragma unroll 8
        for (int i = 0; i < NHID2; ++i) v = fmaf(es[w][i], sWmlp[i][lane], v);
        out[(size_t)node * NHID2 + lane] = v;
    }
}

// ---------------- launcher ----------------
extern "C" void kernel_launch(void* const* d_in, const int* in_sizes, int n_in,
                              void* d_out, int out_size, void* d_ws, size_t ws_size,
                              hipStream_t stream) {
    const float* x    = (const float*)d_in[0];
    const int*   sadj = (const int*)d_in[1];
    const int*   fadj = (const int*)d_in[2];
    const int N = in_sizes[0] / NFEAT;
    const int E = in_sizes[1] / 2;
    const float* Wg1a = (const float*)d_in[3];
    const float* bg1a = (const float*)d_in[4];
    const float* Wg1b = (const float*)d_in[5];
    const float* bg1b = (const float*)d_in[6];
    const float* Wg2a = (const float*)d_in[7];
    const float* bg2a = (const float*)d_in[8];
    const float* Wg2b = (const float*)d_in[9];
    const float* bg2b = (const float*)d_in[10];
    const float* Wa1  = (const float*)d_in[11];
    const float* ba1  = (const float*)d_in[12];
    const float* Wa2  = (const float*)d_in[13];
    const float* Wmlp = (const float*)d_in[14];
    const float* bmlp = (const float*)d_in[15];
    const float* Wd   = (const float*)d_in[16];
    const float* bd   = (const float*)d_in[17];
    const float* bn_g = (const float*)d_in[18];
    const float* bn_b = (const float*)d_in[19];
    const float* bn_m = (const float*)d_in[20];
    const float* bn_v = (const float*)d_in[21];
    const float* Wpi  = (const float*)d_in[22];
    const float* bpi  = (const float*)d_in[23];
    const float* Wv   = (const float*)d_in[24];
    const float* bv   = (const float*)d_in[25];
    const float* Wmu  = (const float*)d_in[26];
    const float* bmu  = (const float*)d_in[27];

    float* out   = (float*)d_out;
    float* emb1  = out;
    float* emb2  = out + (size_t)N * NHID2;
    float* embO  = out + 2 * (size_t)N * NHID2;
    float* pi    = out + 3 * (size_t)N * NHID2;
    float* var_  = pi + (size_t)N * NFEAT;
    float* mean_ = var_ + (size_t)N * NFEAT;

    // workspace layout
    float* xw = (float*)d_ws;                       // N*256
    float* hw = xw + (size_t)N * NHID1;             // N*64
    float* h3 = hw + (size_t)N * NHID2;             // N*64
    int* deg       = (int*)(h3 + (size_t)N * NHID2);
    int* row_start = deg + N;                       // N+1
    int* cursor    = row_start + (N + 1);           // N
    int* csr_src   = cursor + N;                    // E
    // big per-graph temporaries live in not-yet-written output segments
    float* h1 = mean_;   // N*256 scratch (mean segment written last)
    float* h  = var_;    // N*256 scratch (var segment written last)
    float* hdec = xw;    // reuse xw after both graphs done

    const int gy = (N + 63) / 64;
    dim3 blk(256);

    // xw = x @ Wg1a  (bias deferred to agg_combine)
    gemm_kernel<EPI_NONE><<<dim3(NHID1/64, gy), blk, 0, stream>>>(
        x, Wg1a, nullptr, xw, N, NFEAT, NHID1, nullptr, nullptr, nullptr, nullptr);

    for (int g = 0; g < 2; ++g) {
        const int* edges = (g == 0) ? sadj : fadj;
        const int* esrc = edges;
        const int* edst = edges + E;
        float* emb_g = (g == 0) ? emb1 : emb2;

        hipMemsetAsync(deg, 0, (size_t)N * sizeof(int), stream);
        hist_kernel<<<(E + 255) / 256, 256, 0, stream>>>(edst, deg, E);
        scan_kernel<<<1, 1024, 0, stream>>>(deg, row_start, cursor, N);
        scatter_kernel<<<(E + 255) / 256, 256, 0, stream>>>(esrc, edst, cursor, csr_src, E);

        // h1 = relu(xw + agg(xw) + bg1a)
        agg_combine_kernel<NHID1, 4><<<(N + 3) / 4, 256, 0, stream>>>(
            xw, row_start, csr_src, bg1a, h1, N);
        // h = relu(h1 @ Wg1b + bg1b)
        gemm_kernel<EPI_RELU><<<dim3(NHID1/64, gy), blk, 0, stream>>>(
            h1, Wg1b, bg1b, h, N, NHID1, NHID1, nullptr, nullptr, nullptr, nullptr);
        // hw = h @ Wg2a
        gemm_kernel<EPI_NONE><<<dim3(NHID2/64, gy), blk, 0, stream>>>(
            h, Wg2a, nullptr, hw, N, NHID1, NHID2, nullptr, nullptr, nullptr, nullptr);
        // h3 = relu(hw + agg(hw) + bg2a)
        agg_combine_kernel<NHID2, 1><<<(N + 3) / 4, 256, 0, stream>>>(
            hw, row_start, csr_src, bg2a, h3, N);
        // emb_g = h3 @ Wg2b + bg2b
        gemm_kernel<EPI_NONE><<<dim3(NHID2/64, gy), blk, 0, stream>>>(
            h3, Wg2b, bg2b, emb_g, N, NHID2, NHID2, nullptr, nullptr, nullptr, nullptr);
    }

    // attention + mlp -> embO
    attn_mlp_kernel<<<(N + 3) / 4, 256, 0, stream>>>(
        emb1, emb2, Wa1, ba1, Wa2, Wmlp, bmlp, embO, N);

    // decoder: hdec = relu(BN(embO @ Wd + bd))
    gemm_kernel<EPI_BNRELU><<<dim3(NHID1/64, gy), blk, 0, stream>>>(
        embO, Wd, bd, hdec, N, NHID2, NHID1, bn_g, bn_b, bn_m, bn_v);

    // heads
    gemm_kernel<EPI_SIGMOID><<<dim3(NFEAT/64, gy), blk, 0, stream>>>(
        hdec, Wpi, bpi, pi, N, NHID1, NFEAT, nullptr, nullptr, nullptr, nullptr);
    gemm_kernel<EPI_SOFTPLUS><<<dim3(NFEAT/64, gy), blk, 0, stream>>>(
        hdec, Wv, bv, var_, N, NHID1, NFEAT, nullptr, nullptr, nullptr, nullptr);
    gemm_kernel<EPI_EXPCLIP><<<dim3(NFEAT/64, gy), blk, 0, stream>>>(
        hdec, Wmu, bmu, mean_, N, NHID1, NFEAT, nullptr, nullptr, nullptr, nullptr);
}

// Round 2
// 1438.881 us; speedup vs baseline: 1.8092x; 1.8092x over previous
//
#include <hip/hip_runtime.h>
#include <hip/hip_bf16.h>
#include <cstdint>
#include <cstddef>

#define NFEAT 512
#define NHID1 256
#define NHID2 64
#define ATTH  16

typedef __attribute__((ext_vector_type(8))) short short8v;   // 8 bf16 (4 VGPRs)
typedef __attribute__((ext_vector_type(4))) float f32x4;     // mfma accumulator

enum { EPI_NONE=0, EPI_RELU=1, EPI_BNRELU=2, EPI_SIGMOID=3, EPI_SOFTPLUS=4, EPI_EXPCLIP=5 };

static __device__ __forceinline__ float bf2f(unsigned short u) {
    return __uint_as_float(((unsigned int)u) << 16);
}
static __device__ __forceinline__ unsigned short f2bf(float f) {
    __hip_bfloat16 h = __float2bfloat16(f);   // RNE
    return *reinterpret_cast<unsigned short*>(&h);
}

// ---------------- conversion kernels ----------------
__global__ __launch_bounds__(256) void convert_x_kernel(const float* __restrict__ in,
                                                        unsigned short* __restrict__ out, long n4) {
    long i = blockIdx.x * (long)blockDim.x + threadIdx.x;
    long stride = (long)gridDim.x * blockDim.x;
    for (; i < n4; i += stride) {
        float4 v = reinterpret_cast<const float4*>(in)[i];
        ushort4 o;
        o.x = f2bf(v.x); o.y = f2bf(v.y); o.z = f2bf(v.z); o.w = f2bf(v.w);
        reinterpret_cast<ushort4*>(out)[i] = o;
    }
}

// Wt[n][k] = bf16(W[k][n])   (W is [K][Nn] row-major)
__global__ __launch_bounds__(256) void convert_wt_kernel(const float* __restrict__ W,
                                                         unsigned short* __restrict__ Wt,
                                                         int K, int Nn) {
    int idx = blockIdx.x * blockDim.x + threadIdx.x;
    if (idx >= K * Nn) return;
    int n = idx / K, k = idx % K;
    Wt[idx] = f2bf(W[(size_t)k * Nn + n]);
}

// ---------------- bf16 MFMA GEMM: C = epi(A[M,K] @ Bt[Nn,K]^T + bias) ----------------
// 128x128 tile, 4 waves (2x2), 16x16x32 mfma, BK=32, global_load_lds width-16 staging.
template<int EPI, int OUT_BF16>
__global__ __launch_bounds__(256) void mfma_gemm_kernel(
    const unsigned short* __restrict__ A, const unsigned short* __restrict__ Bt,
    const float* __restrict__ bias, void* __restrict__ Cout,
    int M, int K, int Nn,
    const float* __restrict__ bn_g, const float* __restrict__ bn_b,
    const float* __restrict__ bn_m, const float* __restrict__ bn_v)
{
    __shared__ unsigned short As[128 * 32];   // [row][k] linear, 8 KB
    __shared__ unsigned short Bs[128 * 32];   // [col][k] linear, 8 KB
    const int t = threadIdx.x;
    const int w = t >> 6, l = t & 63;
    const int wr = w >> 1, wc = w & 1;
    const int rowBase = blockIdx.y * 128, colBase = blockIdx.x * 128;

    f32x4 acc[4][4];
    #pragma unroll
    for (int m = 0; m < 4; ++m)
        #pragma unroll
        for (int n = 0; n < 4; ++n) acc[m][n] = (f32x4){0.f, 0.f, 0.f, 0.f};

    // staging: 8 chunks of 16 rows x 32 k (1024 B); wave w owns chunks 2w, 2w+1.
    // HW writes LDS at wave-uniform base + lane*16B; global source is per-lane.
    const int c0 = w * 2, c1 = w * 2 + 1;
    const int r0 = c0 * 16 + (l >> 2), r1 = c1 * 16 + (l >> 2);
    const int kid = (l & 3) * 8;
    int ar0 = rowBase + r0; if (ar0 >= M) ar0 = M - 1;
    int ar1 = rowBase + r1; if (ar1 >= M) ar1 = M - 1;
    int br0 = colBase + r0; if (br0 >= Nn) br0 = Nn - 1;
    int br1 = colBase + r1; if (br1 >= Nn) br1 = Nn - 1;
    const unsigned short* a0p = A + (size_t)ar0 * K + kid;
    const unsigned short* a1p = A + (size_t)ar1 * K + kid;
    const unsigned short* b0p = Bt + (size_t)br0 * K + kid;
    const unsigned short* b1p = Bt + (size_t)br1 * K + kid;

    const int frow = (l & 15), fk = (l >> 4) * 8;

    for (int k0 = 0; k0 < K; k0 += 32) {
        __builtin_amdgcn_global_load_lds(
            (const __attribute__((address_space(1))) void*)(a0p + k0),
            (__attribute__((address_space(3))) void*)(As + c0 * 512), 16, 0, 0);
        __builtin_amdgcn_global_load_lds(
            (const __attribute__((address_space(1))) void*)(a1p + k0),
            (__attribute__((address_space(3))) void*)(As + c1 * 512), 16, 0, 0);
        __builtin_amdgcn_global_load_lds(
            (const __attribute__((address_space(1))) void*)(b0p + k0),
            (__attribute__((address_space(3))) void*)(Bs + c0 * 512), 16, 0, 0);
        __builtin_amdgcn_global_load_lds(
            (const __attribute__((address_space(1))) void*)(b1p + k0),
            (__attribute__((address_space(3))) void*)(Bs + c1 * 512), 16, 0, 0);
        __syncthreads();

        short8v a[4], b[4];
        #pragma unroll
        for (int m = 0; m < 4; ++m)
            a[m] = *reinterpret_cast<const short8v*>(As + (wr * 64 + m * 16 + frow) * 32 + fk);
        #pragma unroll
        for (int n = 0; n < 4; ++n)
            b[n] = *reinterpret_cast<const short8v*>(Bs + (wc * 64 + n * 16 + frow) * 32 + fk);
        #pragma unroll
        for (int m = 0; m < 4; ++m)
            #pragma unroll
            for (int n = 0; n < 4; ++n)
                acc[m][n] = __builtin_amdgcn_mfma_f32_16x16x32_bf16(a[m], b[n], acc[m][n], 0, 0, 0);
        __syncthreads();
    }

    // epilogue + store. C/D layout: col = lane&15, row = (lane>>4)*4 + j.
    #pragma unroll
    for (int n = 0; n < 4; ++n) {
        int c = colBase + wc * 64 + n * 16 + (l & 15);
        if (c >= Nn) continue;
        float bia = bias ? bias[c] : 0.f;
        float g = 0.f, bb = 0.f, mm = 0.f, iv = 0.f;
        if (EPI == EPI_BNRELU) {
            g = bn_g[c]; bb = bn_b[c]; mm = bn_m[c];
            iv = rsqrtf(bn_v[c] + 1e-5f);
        }
        #pragma unroll
        for (int m = 0; m < 4; ++m) {
            #pragma unroll
            for (int j = 0; j < 4; ++j) {
                int r = rowBase + wr * 64 + m * 16 + (l >> 4) * 4 + j;
                if (r >= M) continue;
                float v = acc[m][n][j] + bia;
                if (EPI == EPI_RELU) {
                    v = fmaxf(v, 0.f);
                } else if (EPI == EPI_BNRELU) {
                    v = (v - mm) * iv * g + bb;
                    v = fmaxf(v, 0.f);
                } else if (EPI == EPI_SIGMOID) {
                    v = 1.f / (1.f + expf(-v));
                } else if (EPI == EPI_SOFTPLUS) {
                    float sp = (v > 20.f) ? v : log1pf(expf(v));
                    v = fminf(fmaxf(sp, 1e-4f), 1e4f);
                } else if (EPI == EPI_EXPCLIP) {
                    v = fminf(fmaxf(expf(v), 1e-5f), 1e6f);
                }
                if (OUT_BF16)
                    ((unsigned short*)Cout)[(size_t)r * Nn + c] = f2bf(v);
                else
                    ((float*)Cout)[(size_t)r * Nn + c] = v;
            }
        }
    }
}

// ---------------- CSR build ----------------
__global__ void hist_kernel(const int* __restrict__ dst, int* __restrict__ deg, int e) {
    int i = blockIdx.x * blockDim.x + threadIdx.x;
    if (i < e) atomicAdd(&deg[dst[i]], 1);
}

__global__ __launch_bounds__(1024) void scan_kernel(const int* __restrict__ deg,
                                                    int* __restrict__ row_start,
                                                    int* __restrict__ cursor, int n) {
    __shared__ int buf[1024];
    __shared__ int carry_s;
    if (threadIdx.x == 0) carry_s = 0;
    __syncthreads();
    for (int base = 0; base < n; base += 1024) {
        int i = base + (int)threadIdx.x;
        int v = (i < n) ? deg[i] : 0;
        buf[threadIdx.x] = v;
        __syncthreads();
        for (int off = 1; off < 1024; off <<= 1) {
            int tv = (threadIdx.x >= (unsigned)off) ? buf[threadIdx.x - off] : 0;
            __syncthreads();
            buf[threadIdx.x] += tv;
            __syncthreads();
        }
        int carry = carry_s;
        int inc = buf[threadIdx.x];
        if (i < n) {
            int start = carry + inc - v;
            row_start[i] = start;
            cursor[i] = start;
            if (i == n - 1) row_start[n] = carry + inc;
        }
        __syncthreads();
        if (threadIdx.x == 1023) carry_s = carry + buf[1023];
        __syncthreads();
    }
}

__global__ void scatter_kernel(const int* __restrict__ src, const int* __restrict__ dst,
                               int* __restrict__ cursor, int* __restrict__ csr_src, int e) {
    int i = blockIdx.x * blockDim.x + threadIdx.x;
    if (i < e) {
        int pos = atomicAdd(&cursor[dst[i]], 1);
        csr_src[pos] = src[i];
    }
}

// ---------------- gather aggregation (bf16 rows, fp32 accum) ----------------
// out[n,:] = bf16(relu(xw[n,:] + sum_{s in inNbrs(n)} xw[s,:] + bias))
template<int F>
__global__ __launch_bounds__(256) void agg_combine_kernel(
    const unsigned short* __restrict__ xw, const int* __restrict__ row_start,
    const int* __restrict__ csr_src, const float* __restrict__ bias,
    unsigned short* __restrict__ out, int n)
{
    constexpr int LPN = F / 4;                 // lanes per node (4 bf16 each)
    int node = blockIdx.x * (256 / LPN) + (int)threadIdx.x / LPN;
    int lane = (int)threadIdx.x % LPN;
    if (node >= n) return;
    int beg = row_start[node], end = row_start[node + 1];
    float a0 = 0.f, a1 = 0.f, a2 = 0.f, a3 = 0.f;
    int e = beg;
    for (; e + 4 <= end; e += 4) {             // 4 outstanding gathers for latency hiding
        int s0 = csr_src[e], s1 = csr_src[e + 1], s2 = csr_src[e + 2], s3 = csr_src[e + 3];
        ushort4 v0 = *reinterpret_cast<const ushort4*>(xw + (size_t)s0 * F + lane * 4);
        ushort4 v1 = *reinterpret_cast<const ushort4*>(xw + (size_t)s1 * F + lane * 4);
        ushort4 v2 = *reinterpret_cast<const ushort4*>(xw + (size_t)s2 * F + lane * 4);
        ushort4 v3 = *reinterpret_cast<const ushort4*>(xw + (size_t)s3 * F + lane * 4);
        a0 += bf2f(v0.x) + bf2f(v1.x) + bf2f(v2.x) + bf2f(v3.x);
        a1 += bf2f(v0.y) + bf2f(v1.y) + bf2f(v2.y) + bf2f(v3.y);
        a2 += bf2f(v0.z) + bf2f(v1.z) + bf2f(v2.z) + bf2f(v3.z);
        a3 += bf2f(v0.w) + bf2f(v1.w) + bf2f(v2.w) + bf2f(v3.w);
    }
    for (; e < end; ++e) {
        int s = csr_src[e];
        ushort4 v = *reinterpret_cast<const ushort4*>(xw + (size_t)s * F + lane * 4);
        a0 += bf2f(v.x); a1 += bf2f(v.y); a2 += bf2f(v.z); a3 += bf2f(v.w);
    }
    ushort4 sv = *reinterpret_cast<const ushort4*>(xw + (size_t)node * F + lane * 4);
    ushort4 o;
    o.x = f2bf(fmaxf(bf2f(sv.x) + a0 + bias[lane * 4 + 0], 0.f));
    o.y = f2bf(fmaxf(bf2f(sv.y) + a1 + bias[lane * 4 + 1], 0.f));
    o.z = f2bf(fmaxf(bf2f(sv.z) + a2 + bias[lane * 4 + 2], 0.f));
    o.w = f2bf(fmaxf(bf2f(sv.w) + a3 + bias[lane * 4 + 3], 0.f));
    *reinterpret_cast<ushort4*>(out + (size_t)node * F + lane * 4) = o;
}

// ---------------- fused spatial attention + mlp ----------------
__global__ __launch_bounds__(256) void attn_mlp_kernel(
    const float* __restrict__ emb1, const float* __restrict__ emb2,
    const float* __restrict__ Wa1, const float* __restrict__ ba1,
    const float* __restrict__ Wa2, const float* __restrict__ Wmlp,
    const float* __restrict__ bmlp, float* __restrict__ out,
    unsigned short* __restrict__ out_bf, int n)
{
    __shared__ float sWa1[NHID2][ATTH];
    __shared__ float sba1[ATTH], sWa2[ATTH];
    __shared__ float sWmlp[NHID2][NHID2 + 1];
    __shared__ float sbmlp[NHID2];
    __shared__ float zs[4][3][NHID2];
    __shared__ float part[4][3][ATTH];
    __shared__ float sbeta[4][3];
    __shared__ float es[4][NHID2];

    int t = threadIdx.x;
    for (int idx = t; idx < NHID2 * ATTH; idx += 256) sWa1[idx / ATTH][idx % ATTH] = Wa1[idx];
    if (t < ATTH) { sba1[t] = ba1[t]; sWa2[t] = Wa2[t]; }
    for (int idx = t; idx < NHID2 * NHID2; idx += 256) sWmlp[idx / NHID2][idx % NHID2] = Wmlp[idx];
    if (t < NHID2) sbmlp[t] = bmlp[t];

    int w = t >> 6, lane = t & 63;
    int node = blockIdx.x * 4 + w;
    float z0 = 0.f, z2 = 0.f;
    if (node < n) {
        z0 = emb1[(size_t)node * NHID2 + lane];
        z2 = emb2[(size_t)node * NHID2 + lane];
    }
    zs[w][0][lane] = z0;
    zs[w][1][lane] = 0.5f * (z0 + z2);
    zs[w][2][lane] = z2;
    __syncthreads();

    if (t < 192) {
        int ww = t / 48, k = (t / 16) % 3, h = t % 16;
        float p = 0.f;
        #pragma unroll 8
        for (int i = 0; i < NHID2; ++i) p += zs[ww][k][i] * sWa1[i][h];
        part[ww][k][h] = tanhf(p + sba1[h]) * sWa2[h];
    }
    __syncthreads();
    if (t < 12) {
        int ww = t / 3, k = t % 3;
        float s = 0.f;
        #pragma unroll
        for (int h = 0; h < ATTH; ++h) s += part[ww][k][h];
        part[ww][k][0] = s;
    }
    __syncthreads();
    if (t < 4) {
        float w0 = part[t][0][0], w1 = part[t][1][0], w2 = part[t][2][0];
        float m = fmaxf(w0, fmaxf(w1, w2));
        float e0 = expf(w0 - m), e1 = expf(w1 - m), e2 = expf(w2 - m);
        float d = e0 + e1 + e2;
        sbeta[t][0] = e0 / d; sbeta[t][1] = e1 / d; sbeta[t][2] = e2 / d;
    }
    __syncthreads();
    es[w][lane] = sbeta[w][0] * zs[w][0][lane] + sbeta[w][1] * zs[w][1][lane]
                + sbeta[w][2] * zs[w][2][lane];
    __syncthreads();
    if (node < n) {
        float v = sbmlp[lane];
        #pragma unroll 8
        for (int i = 0; i < NHID2; ++i) v = fmaf(es[w][i], sWmlp[i][lane], v);
        out[(size_t)node * NHID2 + lane] = v;
        out_bf[(size_t)node * NHID2 + lane] = f2bf(v);
    }
}

// ---------------- launcher ----------------
extern "C" void kernel_launch(void* const* d_in, const int* in_sizes, int n_in,
                              void* d_out, int out_size, void* d_ws, size_t ws_size,
                              hipStream_t stream) {
    const float* x    = (const float*)d_in[0];
    const int*   sadj = (const int*)d_in[1];
    const int*   fadj = (const int*)d_in[2];
    const int N = in_sizes[0] / NFEAT;
    const int E = in_sizes[1] / 2;
    const float* Wg1a = (const float*)d_in[3];
    const float* bg1a = (const float*)d_in[4];
    const float* Wg1b = (const float*)d_in[5];
    const float* bg1b = (const float*)d_in[6];
    const float* Wg2a = (const float*)d_in[7];
    const float* bg2a = (const float*)d_in[8];
    const float* Wg2b = (const float*)d_in[9];
    const float* bg2b = (const float*)d_in[10];
    const float* Wa1  = (const float*)d_in[11];
    const float* ba1  = (const float*)d_in[12];
    const float* Wa2  = (const float*)d_in[13];
    const float* Wmlp = (const float*)d_in[14];
    const float* bmlp = (const float*)d_in[15];
    const float* Wd   = (const float*)d_in[16];
    const float* bd   = (const float*)d_in[17];
    const float* bn_g = (const float*)d_in[18];
    const float* bn_b = (const float*)d_in[19];
    const float* bn_m = (const float*)d_in[20];
    const float* bn_v = (const float*)d_in[21];
    const float* Wpi  = (const float*)d_in[22];
    const float* bpi  = (const float*)d_in[23];
    const float* Wv   = (const float*)d_in[24];
    const float* bv   = (const float*)d_in[25];
    const float* Wmu  = (const float*)d_in[26];
    const float* bmu  = (const float*)d_in[27];

    float* out   = (float*)d_out;
    float* emb1  = out;
    float* emb2  = out + (size_t)N * NHID2;
    float* embO  = out + 2 * (size_t)N * NHID2;
    float* pi    = out + 3 * (size_t)N * NHID2;
    float* var_  = pi + (size_t)N * NFEAT;
    float* mean_ = var_ + (size_t)N * NFEAT;

    // ---- workspace carve (256B aligned) ----
    char* wsb = (char*)d_ws;
    auto alloc = [&](size_t bytes) { char* p = wsb; wsb += (bytes + 255) & ~(size_t)255; return p; };
    unsigned short* xw_bf   = (unsigned short*)alloc((size_t)N * NHID1 * 2);
    unsigned short* hw_bf   = (unsigned short*)alloc((size_t)N * NHID2 * 2);
    unsigned short* h3_bf   = (unsigned short*)alloc((size_t)N * NHID2 * 2);
    unsigned short* embO_bf = (unsigned short*)alloc((size_t)N * NHID2 * 2);
    unsigned short* hdec_bf = (unsigned short*)alloc((size_t)N * NHID1 * 2);
    unsigned short* Wg1a_t  = (unsigned short*)alloc((size_t)NFEAT * NHID1 * 2);
    unsigned short* Wg1b_t  = (unsigned short*)alloc((size_t)NHID1 * NHID1 * 2);
    unsigned short* Wg2a_t  = (unsigned short*)alloc((size_t)NHID1 * NHID2 * 2);
    unsigned short* Wg2b_t  = (unsigned short*)alloc((size_t)NHID2 * NHID2 * 2);
    unsigned short* Wd_t    = (unsigned short*)alloc((size_t)NHID2 * NHID1 * 2);
    unsigned short* Wpi_t   = (unsigned short*)alloc((size_t)NHID1 * NFEAT * 2);
    unsigned short* Wv_t    = (unsigned short*)alloc((size_t)NHID1 * NFEAT * 2);
    unsigned short* Wmu_t   = (unsigned short*)alloc((size_t)NHID1 * NFEAT * 2);
    int* deg       = (int*)alloc((size_t)N * 4);
    int* row_start = (int*)alloc((size_t)(N + 1) * 4);
    int* cursor    = (int*)alloc((size_t)N * 4);
    int* csr_src   = (int*)alloc((size_t)E * 4);

    // big transient bf16 buffers live in not-yet-written output segments
    unsigned short* x_bf  = (unsigned short*)mean_;  // N*512 bf16, dead after xw gemm
    unsigned short* h1_bf = (unsigned short*)pi;     // N*256 bf16, per-graph
    unsigned short* h_bf  = (unsigned short*)var_;   // N*256 bf16, per-graph

    const int gy = (N + 127) / 128;

    // ---- weight/input conversion ----
    convert_x_kernel<<<2048, 256, 0, stream>>>(x, x_bf, (long)N * NFEAT / 4);
    convert_wt_kernel<<<(NFEAT*NHID1 + 255)/256, 256, 0, stream>>>(Wg1a, Wg1a_t, NFEAT, NHID1);
    convert_wt_kernel<<<(NHID1*NHID1 + 255)/256, 256, 0, stream>>>(Wg1b, Wg1b_t, NHID1, NHID1);
    convert_wt_kernel<<<(NHID1*NHID2 + 255)/256, 256, 0, stream>>>(Wg2a, Wg2a_t, NHID1, NHID2);
    convert_wt_kernel<<<(NHID2*NHID2 + 255)/256, 256, 0, stream>>>(Wg2b, Wg2b_t, NHID2, NHID2);
    convert_wt_kernel<<<(NHID2*NHID1 + 255)/256, 256, 0, stream>>>(Wd,   Wd_t,   NHID2, NHID1);
    convert_wt_kernel<<<(NHID1*NFEAT + 255)/256, 256, 0, stream>>>(Wpi,  Wpi_t,  NHID1, NFEAT);
    convert_wt_kernel<<<(NHID1*NFEAT + 255)/256, 256, 0, stream>>>(Wv,   Wv_t,   NHID1, NFEAT);
    convert_wt_kernel<<<(NHID1*NFEAT + 255)/256, 256, 0, stream>>>(Wmu,  Wmu_t,  NHID1, NFEAT);

    // xw = x @ Wg1a (bias deferred to agg)
    mfma_gemm_kernel<EPI_NONE,1><<<dim3(2, gy), 256, 0, stream>>>(
        x_bf, Wg1a_t, nullptr, xw_bf, N, NFEAT, NHID1, nullptr, nullptr, nullptr, nullptr);

    for (int g = 0; g < 2; ++g) {
        const int* edges = (g == 0) ? sadj : fadj;
        const int* esrc = edges;
        const int* edst = edges + E;
        float* emb_g = (g == 0) ? emb1 : emb2;

        hipMemsetAsync(deg, 0, (size_t)N * sizeof(int), stream);
        hist_kernel<<<(E + 255) / 256, 256, 0, stream>>>(edst, deg, E);
        scan_kernel<<<1, 1024, 0, stream>>>(deg, row_start, cursor, N);
        scatter_kernel<<<(E + 255) / 256, 256, 0, stream>>>(esrc, edst, cursor, csr_src, E);

        // h1 = relu(xw + agg(xw) + bg1a)
        agg_combine_kernel<NHID1><<<(N + 3) / 4, 256, 0, stream>>>(
            xw_bf, row_start, csr_src, bg1a, h1_bf, N);
        // h = relu(h1 @ Wg1b + bg1b)
        mfma_gemm_kernel<EPI_RELU,1><<<dim3(2, gy), 256, 0, stream>>>(
            h1_bf, Wg1b_t, bg1b, h_bf, N, NHID1, NHID1, nullptr, nullptr, nullptr, nullptr);
        // hw = h @ Wg2a
        mfma_gemm_kernel<EPI_NONE,1><<<dim3(1, gy), 256, 0, stream>>>(
            h_bf, Wg2a_t, nullptr, hw_bf, N, NHID1, NHID2, nullptr, nullptr, nullptr, nullptr);
        // h3 = relu(hw + agg(hw) + bg2a)
        agg_combine_kernel<NHID2><<<(N + 15) / 16, 256, 0, stream>>>(
            hw_bf, row_start, csr_src, bg2a, h3_bf, N);
        // emb_g = h3 @ Wg2b + bg2b  (fp32 final output)
        mfma_gemm_kernel<EPI_NONE,0><<<dim3(1, gy), 256, 0, stream>>>(
            h3_bf, Wg2b_t, bg2b, emb_g, N, NHID2, NHID2, nullptr, nullptr, nullptr, nullptr);
    }

    // attention + mlp -> embO (fp32) + embO_bf
    attn_mlp_kernel<<<(N + 3) / 4, 256, 0, stream>>>(
        emb1, emb2, Wa1, ba1, Wa2, Wmlp, bmlp, embO, embO_bf, N);

    // decoder: hdec = relu(BN(embO @ Wd + bd))  (bf16 for heads)
    mfma_gemm_kernel<EPI_BNRELU,1><<<dim3(2, gy), 256, 0, stream>>>(
        embO_bf, Wd_t, bd, hdec_bf, N, NHID2, NHID1, bn_g, bn_b, bn_m, bn_v);

    // heads (fp32 final outputs)
    mfma_gemm_kernel<EPI_SIGMOID,0><<<dim3(4, gy), 256, 0, stream>>>(
        hdec_bf, Wpi_t, bpi, pi, N, NHID1, NFEAT, nullptr, nullptr, nullptr, nullptr);
    mfma_gemm_kernel<EPI_SOFTPLUS,0><<<dim3(4, gy), 256, 0, stream>>>(
        hdec_bf, Wv_t, bv, var_, N, NHID1, NFEAT, nullptr, nullptr, nullptr, nullptr);
    mfma_gemm_kernel<EPI_EXPCLIP,0><<<dim3(4, gy), 256, 0, stream>>>(
        hdec_bf, Wmu_t, bmu, mean_, N, NHID1, NFEAT, nullptr, nullptr, nullptr, nullptr);
}

// Round 3
// 1239.012 us; speedup vs baseline: 2.1010x; 1.1613x over previous
//
#include <hip/hip_runtime.h>
#include <hip/hip_bf16.h>
#include <cstdint>
#include <cstddef>

#define NFEAT 512
#define NHID1 256
#define NHID2 64
#define ATTH  16

typedef __attribute__((ext_vector_type(8))) short short8v;           // 8 bf16 (4 VGPRs)
typedef __attribute__((ext_vector_type(8))) unsigned short ushort8v; // 16B load
typedef __attribute__((ext_vector_type(4))) float f32x4;             // mfma accumulator

enum { EPI_NONE=0, EPI_RELU=1, EPI_BNRELU=2, EPI_SIGMOID=3, EPI_SOFTPLUS=4, EPI_EXPCLIP=5 };

static __device__ __forceinline__ float bf2f(unsigned short u) {
    return __uint_as_float(((unsigned int)u) << 16);
}
static __device__ __forceinline__ unsigned short f2bf(float f) {
    __hip_bfloat16 h = __float2bfloat16(f);   // RNE
    return *reinterpret_cast<unsigned short*>(&h);
}

// ---------------- conversion kernels ----------------
__global__ __launch_bounds__(256) void convert_x_kernel(const float* __restrict__ in,
                                                        unsigned short* __restrict__ out, long n4) {
    long i = blockIdx.x * (long)blockDim.x + threadIdx.x;
    long stride = (long)gridDim.x * blockDim.x;
    for (; i < n4; i += stride) {
        float4 v = reinterpret_cast<const float4*>(in)[i];
        ushort4 o;
        o.x = f2bf(v.x); o.y = f2bf(v.y); o.z = f2bf(v.z); o.w = f2bf(v.w);
        reinterpret_cast<ushort4*>(out)[i] = o;
    }
}

struct WSpec { const float* W; unsigned short* Wt; int K, Nn; };
struct WPack { WSpec s[8]; };

// Wt[n][k] = bf16(W[k][n]) for all 8 weights in one launch; grid.y = weight id
__global__ __launch_bounds__(256) void convert_wt_all_kernel(WPack p) {
    WSpec sp = p.s[blockIdx.y];
    int total = sp.K * sp.Nn;
    for (int idx = blockIdx.x * 256 + threadIdx.x; idx < total; idx += gridDim.x * 256) {
        int n = idx / sp.K, k = idx % sp.K;
        sp.Wt[idx] = f2bf(sp.W[(size_t)k * sp.Nn + n]);
    }
}

// ---------------- bf16 MFMA GEMM: C = epi(A[M,K] @ Bt[Nn,K]^T + bias) ----------------
// 128x128 tile, 4 waves (2x2), 16x16x32 mfma, BK=32, global_load_lds width-16 staging.
// (unchanged from round 2 — bit-identical numerics)
template<int EPI, int OUT_BF16>
__global__ __launch_bounds__(256) void mfma_gemm_kernel(
    const unsigned short* __restrict__ A, const unsigned short* __restrict__ Bt,
    const float* __restrict__ bias, void* __restrict__ Cout,
    int M, int K, int Nn,
    const float* __restrict__ bn_g, const float* __restrict__ bn_b,
    const float* __restrict__ bn_m, const float* __restrict__ bn_v)
{
    __shared__ unsigned short As[128 * 32];
    __shared__ unsigned short Bs[128 * 32];
    const int t = threadIdx.x;
    const int w = t >> 6, l = t & 63;
    const int wr = w >> 1, wc = w & 1;
    const int rowBase = blockIdx.y * 128, colBase = blockIdx.x * 128;

    f32x4 acc[4][4];
    #pragma unroll
    for (int m = 0; m < 4; ++m)
        #pragma unroll
        for (int n = 0; n < 4; ++n) acc[m][n] = (f32x4){0.f, 0.f, 0.f, 0.f};

    const int c0 = w * 2, c1 = w * 2 + 1;
    const int r0 = c0 * 16 + (l >> 2), r1 = c1 * 16 + (l >> 2);
    const int kid = (l & 3) * 8;
    int ar0 = rowBase + r0; if (ar0 >= M) ar0 = M - 1;
    int ar1 = rowBase + r1; if (ar1 >= M) ar1 = M - 1;
    int br0 = colBase + r0; if (br0 >= Nn) br0 = Nn - 1;
    int br1 = colBase + r1; if (br1 >= Nn) br1 = Nn - 1;
    const unsigned short* a0p = A + (size_t)ar0 * K + kid;
    const unsigned short* a1p = A + (size_t)ar1 * K + kid;
    const unsigned short* b0p = Bt + (size_t)br0 * K + kid;
    const unsigned short* b1p = Bt + (size_t)br1 * K + kid;

    const int frow = (l & 15), fk = (l >> 4) * 8;

    for (int k0 = 0; k0 < K; k0 += 32) {
        __builtin_amdgcn_global_load_lds(
            (const __attribute__((address_space(1))) void*)(a0p + k0),
            (__attribute__((address_space(3))) void*)(As + c0 * 512), 16, 0, 0);
        __builtin_amdgcn_global_load_lds(
            (const __attribute__((address_space(1))) void*)(a1p + k0),
            (__attribute__((address_space(3))) void*)(As + c1 * 512), 16, 0, 0);
        __builtin_amdgcn_global_load_lds(
            (const __attribute__((address_space(1))) void*)(b0p + k0),
            (__attribute__((address_space(3))) void*)(Bs + c0 * 512), 16, 0, 0);
        __builtin_amdgcn_global_load_lds(
            (const __attribute__((address_space(1))) void*)(b1p + k0),
            (__attribute__((address_space(3))) void*)(Bs + c1 * 512), 16, 0, 0);
        __syncthreads();

        short8v a[4], b[4];
        #pragma unroll
        for (int m = 0; m < 4; ++m)
            a[m] = *reinterpret_cast<const short8v*>(As + (wr * 64 + m * 16 + frow) * 32 + fk);
        #pragma unroll
        for (int n = 0; n < 4; ++n)
            b[n] = *reinterpret_cast<const short8v*>(Bs + (wc * 64 + n * 16 + frow) * 32 + fk);
        #pragma unroll
        for (int m = 0; m < 4; ++m)
            #pragma unroll
            for (int n = 0; n < 4; ++n)
                acc[m][n] = __builtin_amdgcn_mfma_f32_16x16x32_bf16(a[m], b[n], acc[m][n], 0, 0, 0);
        __syncthreads();
    }

    #pragma unroll
    for (int n = 0; n < 4; ++n) {
        int c = colBase + wc * 64 + n * 16 + (l & 15);
        if (c >= Nn) continue;
        float bia = bias ? bias[c] : 0.f;
        float g = 0.f, bb = 0.f, mm = 0.f, iv = 0.f;
        if (EPI == EPI_BNRELU) {
            g = bn_g[c]; bb = bn_b[c]; mm = bn_m[c];
            iv = rsqrtf(bn_v[c] + 1e-5f);
        }
        #pragma unroll
        for (int m = 0; m < 4; ++m) {
            #pragma unroll
            for (int j = 0; j < 4; ++j) {
                int r = rowBase + wr * 64 + m * 16 + (l >> 4) * 4 + j;
                if (r >= M) continue;
                float v = acc[m][n][j] + bia;
                if (EPI == EPI_RELU) {
                    v = fmaxf(v, 0.f);
                } else if (EPI == EPI_BNRELU) {
                    v = (v - mm) * iv * g + bb;
                    v = fmaxf(v, 0.f);
                } else if (EPI == EPI_SIGMOID) {
                    v = 1.f / (1.f + expf(-v));
                } else if (EPI == EPI_SOFTPLUS) {
                    float sp = (v > 20.f) ? v : log1pf(expf(v));
                    v = fminf(fmaxf(sp, 1e-4f), 1e4f);
                } else if (EPI == EPI_EXPCLIP) {
                    v = fminf(fmaxf(expf(v), 1e-5f), 1e6f);
                }
                if (OUT_BF16)
                    ((unsigned short*)Cout)[(size_t)r * Nn + c] = f2bf(v);
                else
                    ((float*)Cout)[(size_t)r * Nn + c] = v;
            }
        }
    }
}

// ---------------- combined CSR build (both graphs, rows 0..2N-1) ----------------
__global__ void hist2_kernel(const int* __restrict__ edst0, const int* __restrict__ edst1,
                             int* __restrict__ deg, int e, int nHalf) {
    int i = blockIdx.x * blockDim.x + threadIdx.x;
    if (i < 2 * e) {
        int d = (i < e) ? edst0[i] : (edst1[i - e] + nHalf);
        atomicAdd(&deg[d], 1);
    }
}

// multi-block scan: pass 1 — per-block exclusive scan + block sums
__global__ __launch_bounds__(1024) void scan_block_kernel(const int* __restrict__ deg,
                                                          int* __restrict__ excl,
                                                          int* __restrict__ bsum, int n) {
    __shared__ int buf[1024];
    int i = blockIdx.x * 1024 + (int)threadIdx.x;
    int v = (i < n) ? deg[i] : 0;
    buf[threadIdx.x] = v;
    __syncthreads();
    for (int off = 1; off < 1024; off <<= 1) {
        int tv = (threadIdx.x >= (unsigned)off) ? buf[threadIdx.x - off] : 0;
        __syncthreads();
        buf[threadIdx.x] += tv;
        __syncthreads();
    }
    if (i < n) excl[i] = buf[threadIdx.x] - v;
    if (threadIdx.x == 1023) bsum[blockIdx.x] = buf[1023];
}

// pass 2 — exclusive scan of block sums (single block, nb <= 1024)
__global__ __launch_bounds__(1024) void scan_tops_kernel(int* __restrict__ bsum, int nb) {
    __shared__ int buf[1024];
    int v = ((int)threadIdx.x < nb) ? bsum[threadIdx.x] : 0;
    buf[threadIdx.x] = v;
    __syncthreads();
    for (int off = 1; off < 1024; off <<= 1) {
        int tv = (threadIdx.x >= (unsigned)off) ? buf[threadIdx.x - off] : 0;
        __syncthreads();
        buf[threadIdx.x] += tv;
        __syncthreads();
    }
    if ((int)threadIdx.x < nb) bsum[threadIdx.x] = buf[threadIdx.x] - v;
}

// pass 3 — add block offsets, emit row_start + cursor + total
__global__ void scan_add_kernel(int* __restrict__ row_start, const int* __restrict__ bsum,
                                const int* __restrict__ deg, int* __restrict__ cursor, int n) {
    int i = blockIdx.x * blockDim.x + threadIdx.x;
    if (i < n) {
        int s = row_start[i] + bsum[i >> 10];
        row_start[i] = s;
        cursor[i] = s;
        if (i == n - 1) row_start[n] = s + deg[i];
    }
}

__global__ void scatter2_kernel(const int* __restrict__ sadj, const int* __restrict__ fadj,
                                int* __restrict__ cursor, int* __restrict__ csr_src,
                                int e, int nHalf) {
    int i = blockIdx.x * blockDim.x + threadIdx.x;
    if (i < 2 * e) {
        int src, d;
        if (i < e) { src = sadj[i];     d = sadj[e + i]; }
        else       { src = fadj[i - e]; d = fadj[e + i - e] + nHalf; }
        int pos = atomicAdd(&cursor[d], 1);
        csr_src[pos] = src;   // raw source row 0..nHalf-1
    }
}

// ---------------- gather aggregation (bf16 rows, fp32 accum) ----------------
// out[i,:] = bf16(relu(self[i,:] + sum_{s in row i} xin[base+s,:] + bias))
// SRC_OFFSET=false: xin has nHalf rows (shared by both graphs), self = xin[i mod nHalf]
// SRC_OFFSET=true:  xin has n2 rows, gather base = (i>=nHalf)?nHalf:0, self = xin[i]
template<int F, bool SRC_OFFSET>
__global__ __launch_bounds__(256) void agg_combine_kernel(
    const unsigned short* __restrict__ xin, const int* __restrict__ row_start,
    const int* __restrict__ csr_src, const float* __restrict__ bias,
    unsigned short* __restrict__ out, int n2, int nHalf)
{
    constexpr int LPN = F / 8;                 // lanes per node, 8 bf16 (16B) each
    int node = blockIdx.x * (256 / LPN) + (int)threadIdx.x / LPN;
    int lane = (int)threadIdx.x % LPN;
    if (node >= n2) return;
    const int srcAdd  = (SRC_OFFSET && node >= nHalf) ? nHalf : 0;
    const int selfIdx = SRC_OFFSET ? node : (node >= nHalf ? node - nHalf : node);
    int beg = row_start[node], end = row_start[node + 1];
    float a[8];
    #pragma unroll
    for (int j = 0; j < 8; ++j) a[j] = 0.f;
    int e = beg;
    for (; e + 4 <= end; e += 4) {
        int s0 = csr_src[e] + srcAdd, s1 = csr_src[e+1] + srcAdd;
        int s2 = csr_src[e+2] + srcAdd, s3 = csr_src[e+3] + srcAdd;
        ushort8v v0 = *reinterpret_cast<const ushort8v*>(xin + (size_t)s0 * F + lane * 8);
        ushort8v v1 = *reinterpret_cast<const ushort8v*>(xin + (size_t)s1 * F + lane * 8);
        ushort8v v2 = *reinterpret_cast<const ushort8v*>(xin + (size_t)s2 * F + lane * 8);
        ushort8v v3 = *reinterpret_cast<const ushort8v*>(xin + (size_t)s3 * F + lane * 8);
        #pragma unroll
        for (int j = 0; j < 8; ++j)
            a[j] += bf2f(v0[j]) + bf2f(v1[j]) + bf2f(v2[j]) + bf2f(v3[j]);
    }
    for (; e < end; ++e) {
        int s = csr_src[e] + srcAdd;
        ushort8v v = *reinterpret_cast<const ushort8v*>(xin + (size_t)s * F + lane * 8);
        #pragma unroll
        for (int j = 0; j < 8; ++j) a[j] += bf2f(v[j]);
    }
    ushort8v sv = *reinterpret_cast<const ushort8v*>(xin + (size_t)selfIdx * F + lane * 8);
    ushort8v o;
    #pragma unroll
    for (int j = 0; j < 8; ++j)
        o[j] = f2bf(fmaxf(bf2f(sv[j]) + a[j] + bias[lane * 8 + j], 0.f));
    *reinterpret_cast<ushort8v*>(out + (size_t)node * F + lane * 8) = o;
}

// ---------------- fused spatial attention + mlp (16 nodes/block) ----------------
__global__ __launch_bounds__(256) void attn_mlp_kernel(
    const float* __restrict__ emb1, const float* __restrict__ emb2,
    const float* __restrict__ Wa1, const float* __restrict__ ba1,
    const float* __restrict__ Wa2, const float* __restrict__ Wmlp,
    const float* __restrict__ bmlp, float* __restrict__ out,
    unsigned short* __restrict__ out_bf, int n)
{
    __shared__ float sWa1[NHID2][ATTH];
    __shared__ float sba1[ATTH], sWa2[ATTH];
    __shared__ float sWmlp[NHID2][NHID2 + 1];
    __shared__ float sbmlp[NHID2];
    __shared__ float zs[4][3][NHID2 + 1];   // padded: kills multi-row bank conflict
    __shared__ float part[4][3][ATTH];
    __shared__ float sbeta[4][3];
    __shared__ float es[4][NHID2 + 1];

    int t = threadIdx.x;
    for (int idx = t; idx < NHID2 * ATTH; idx += 256) sWa1[idx / ATTH][idx % ATTH] = Wa1[idx];
    if (t < ATTH) { sba1[t] = ba1[t]; sWa2[t] = Wa2[t]; }
    for (int idx = t; idx < NHID2 * NHID2; idx += 256) sWmlp[idx / NHID2][idx % NHID2] = Wmlp[idx];
    if (t < NHID2) sbmlp[t] = bmlp[t];

    int w = t >> 6, lane = t & 63;

    for (int rep = 0; rep < 4; ++rep) {
        int node = blockIdx.x * 16 + rep * 4 + w;
        float z0 = 0.f, z2 = 0.f;
        if (node < n) {
            z0 = emb1[(size_t)node * NHID2 + lane];
            z2 = emb2[(size_t)node * NHID2 + lane];
        }
        zs[w][0][lane] = z0;
        zs[w][1][lane] = 0.5f * (z0 + z2);
        zs[w][2][lane] = z2;
        __syncthreads();

        if (t < 192) {
            int ww = t / 48, k = (t / 16) % 3, h = t % 16;
            float p = 0.f;
            #pragma unroll 8
            for (int i = 0; i < NHID2; ++i) p += zs[ww][k][i] * sWa1[i][h];
            part[ww][k][h] = tanhf(p + sba1[h]) * sWa2[h];
        }
        __syncthreads();
        if (t < 12) {
            int ww = t / 3, k = t % 3;
            float s = 0.f;
            #pragma unroll
            for (int h = 0; h < ATTH; ++h) s += part[ww][k][h];
            part[ww][k][0] = s;
        }
        __syncthreads();
        if (t < 4) {
            float w0 = part[t][0][0], w1 = part[t][1][0], w2 = part[t][2][0];
            float m = fmaxf(w0, fmaxf(w1, w2));
            float e0 = expf(w0 - m), e1 = expf(w1 - m), e2 = expf(w2 - m);
            float d = e0 + e1 + e2;
            sbeta[t][0] = e0 / d; sbeta[t][1] = e1 / d; sbeta[t][2] = e2 / d;
        }
        __syncthreads();
        es[w][lane] = sbeta[w][0] * zs[w][0][lane] + sbeta[w][1] * zs[w][1][lane]
                    + sbeta[w][2] * zs[w][2][lane];
        __syncthreads();
        if (node < n) {
            float v = sbmlp[lane];
            #pragma unroll 8
            for (int i = 0; i < NHID2; ++i) v = fmaf(es[w][i], sWmlp[i][lane], v);
            out[(size_t)node * NHID2 + lane] = v;
            out_bf[(size_t)node * NHID2 + lane] = f2bf(v);
        }
        __syncthreads();
    }
}

// ---------------- launcher ----------------
extern "C" void kernel_launch(void* const* d_in, const int* in_sizes, int n_in,
                              void* d_out, int out_size, void* d_ws, size_t ws_size,
                              hipStream_t stream) {
    const float* x    = (const float*)d_in[0];
    const int*   sadj = (const int*)d_in[1];
    const int*   fadj = (const int*)d_in[2];
    const int N = in_sizes[0] / NFEAT;
    const int E = in_sizes[1] / 2;
    const int N2 = 2 * N;
    const float* Wg1a = (const float*)d_in[3];
    const float* bg1a = (const float*)d_in[4];
    const float* Wg1b = (const float*)d_in[5];
    const float* bg1b = (const float*)d_in[6];
    const float* Wg2a = (const float*)d_in[7];
    const float* bg2a = (const float*)d_in[8];
    const float* Wg2b = (const float*)d_in[9];
    const float* bg2b = (const float*)d_in[10];
    const float* Wa1  = (const float*)d_in[11];
    const float* ba1  = (const float*)d_in[12];
    const float* Wa2  = (const float*)d_in[13];
    const float* Wmlp = (const float*)d_in[14];
    const float* bmlp = (const float*)d_in[15];
    const float* Wd   = (const float*)d_in[16];
    const float* bd   = (const float*)d_in[17];
    const float* bn_g = (const float*)d_in[18];
    const float* bn_b = (const float*)d_in[19];
    const float* bn_m = (const float*)d_in[20];
    const float* bn_v = (const float*)d_in[21];
    const float* Wpi  = (const float*)d_in[22];
    const float* bpi  = (const float*)d_in[23];
    const float* Wv   = (const float*)d_in[24];
    const float* bv   = (const float*)d_in[25];
    const float* Wmu  = (const float*)d_in[26];
    const float* bmu  = (const float*)d_in[27];

    float* out   = (float*)d_out;
    float* emb1  = out;                              // [N,64]
    float* embO  = out + 2 * (size_t)N * NHID2;      // [N,64]
    float* pi    = out + 3 * (size_t)N * NHID2;      // [N,512]
    float* var_  = pi + (size_t)N * NFEAT;           // [N,512]
    float* mean_ = var_ + (size_t)N * NFEAT;         // [N,512]

    // ---- workspace carve (256B aligned) ----
    char* wsb = (char*)d_ws;
    auto alloc = [&](size_t bytes) { char* p = wsb; wsb += (bytes + 255) & ~(size_t)255; return p; };
    unsigned short* xw_bf   = (unsigned short*)alloc((size_t)N  * NHID1 * 2);
    unsigned short* hw_bf   = (unsigned short*)alloc((size_t)N2 * NHID2 * 2);
    unsigned short* h3_bf   = (unsigned short*)alloc((size_t)N2 * NHID2 * 2);
    unsigned short* embO_bf = (unsigned short*)alloc((size_t)N  * NHID2 * 2);
    unsigned short* hdec_bf = (unsigned short*)alloc((size_t)N  * NHID1 * 2);
    unsigned short* Wg1a_t  = (unsigned short*)alloc((size_t)NFEAT * NHID1 * 2);
    unsigned short* Wg1b_t  = (unsigned short*)alloc((size_t)NHID1 * NHID1 * 2);
    unsigned short* Wg2a_t  = (unsigned short*)alloc((size_t)NHID1 * NHID2 * 2);
    unsigned short* Wg2b_t  = (unsigned short*)alloc((size_t)NHID2 * NHID2 * 2);
    unsigned short* Wd_t    = (unsigned short*)alloc((size_t)NHID2 * NHID1 * 2);
    unsigned short* Wpi_t   = (unsigned short*)alloc((size_t)NHID1 * NFEAT * 2);
    unsigned short* Wv_t    = (unsigned short*)alloc((size_t)NHID1 * NFEAT * 2);
    unsigned short* Wmu_t   = (unsigned short*)alloc((size_t)NHID1 * NFEAT * 2);
    int* deg       = (int*)alloc((size_t)N2 * 4);
    int* row_start = (int*)alloc((size_t)(N2 + 1) * 4);
    int* cursor    = (int*)alloc((size_t)N2 * 4);
    int* bsum      = (int*)alloc((size_t)1024 * 4);
    int* csr_src   = (int*)alloc((size_t)2 * E * 4);

    // big transient bf16 buffers live in not-yet-written output head segments
    unsigned short* x_bf  = (unsigned short*)mean_;  // [N,512]  bf16 (51.2 MB <= 102.4)
    unsigned short* h1_bf = (unsigned short*)pi;     // [2N,256] bf16 (51.2 MB <= 102.4)
    unsigned short* h_bf  = (unsigned short*)var_;   // [2N,256] bf16 (51.2 MB <= 102.4)

    const int gyN  = (N + 127) / 128;
    const int gyN2 = (N2 + 127) / 128;
    const int nb   = (N2 + 1023) / 1024;

    // ---- conversions ----
    convert_x_kernel<<<2048, 256, 0, stream>>>(x, x_bf, (long)N * NFEAT / 4);
    WPack wp;
    wp.s[0] = {Wg1a, Wg1a_t, NFEAT, NHID1};
    wp.s[1] = {Wg1b, Wg1b_t, NHID1, NHID1};
    wp.s[2] = {Wg2a, Wg2a_t, NHID1, NHID2};
    wp.s[3] = {Wg2b, Wg2b_t, NHID2, NHID2};
    wp.s[4] = {Wd,   Wd_t,   NHID2, NHID1};
    wp.s[5] = {Wpi,  Wpi_t,  NHID1, NFEAT};
    wp.s[6] = {Wv,   Wv_t,   NHID1, NFEAT};
    wp.s[7] = {Wmu,  Wmu_t,  NHID1, NFEAT};
    convert_wt_all_kernel<<<dim3(64, 8), 256, 0, stream>>>(wp);

    // ---- combined CSR build (both graphs) ----
    hipMemsetAsync(deg, 0, (size_t)N2 * sizeof(int), stream);
    hist2_kernel<<<(2 * E + 255) / 256, 256, 0, stream>>>(sadj + E, fadj + E, deg, E, N);
    scan_block_kernel<<<nb, 1024, 0, stream>>>(deg, row_start, bsum, N2);
    scan_tops_kernel<<<1, 1024, 0, stream>>>(bsum, nb);
    scan_add_kernel<<<(N2 + 255) / 256, 256, 0, stream>>>(row_start, bsum, deg, cursor, N2);
    scatter2_kernel<<<(2 * E + 255) / 256, 256, 0, stream>>>(sadj, fadj, cursor, csr_src, E, N);

    // ---- GIN, both graphs batched as M = 2N ----
    // xw = x @ Wg1a
    mfma_gemm_kernel<EPI_NONE,1><<<dim3(2, gyN), 256, 0, stream>>>(
        x_bf, Wg1a_t, nullptr, xw_bf, N, NFEAT, NHID1, nullptr, nullptr, nullptr, nullptr);
    // h1 = relu(xw_self + agg(xw) + bg1a)   [2N,256]
    agg_combine_kernel<NHID1,false><<<(N2 * (NHID1/8) + 255) / 256, 256, 0, stream>>>(
        xw_bf, row_start, csr_src, bg1a, h1_bf, N2, N);
    // h = relu(h1 @ Wg1b + bg1b)            [2N,256]
    mfma_gemm_kernel<EPI_RELU,1><<<dim3(2, gyN2), 256, 0, stream>>>(
        h1_bf, Wg1b_t, bg1b, h_bf, N2, NHID1, NHID1, nullptr, nullptr, nullptr, nullptr);
    // hw = h @ Wg2a                         [2N,64]
    mfma_gemm_kernel<EPI_NONE,1><<<dim3(1, gyN2), 256, 0, stream>>>(
        h_bf, Wg2a_t, nullptr, hw_bf, N2, NHID1, NHID2, nullptr, nullptr, nullptr, nullptr);
    // h3 = relu(hw_self + agg(hw) + bg2a)   [2N,64]
    agg_combine_kernel<NHID2,true><<<(N2 * (NHID2/8) + 255) / 256, 256, 0, stream>>>(
        hw_bf, row_start, csr_src, bg2a, h3_bf, N2, N);
    // emb1‖emb2 = h3 @ Wg2b + bg2b  (fp32, contiguous in d_out)
    mfma_gemm_kernel<EPI_NONE,0><<<dim3(1, gyN2), 256, 0, stream>>>(
        h3_bf, Wg2b_t, bg2b, emb1, N2, NHID2, NHID2, nullptr, nullptr, nullptr, nullptr);

    // ---- attention + mlp -> embO (fp32) + embO_bf ----
    attn_mlp_kernel<<<(N + 15) / 16, 256, 0, stream>>>(
        emb1, emb1 + (size_t)N * NHID2, Wa1, ba1, Wa2, Wmlp, bmlp, embO, embO_bf, N);

    // ---- decoder: hdec = relu(BN(embO @ Wd + bd)) ----
    mfma_gemm_kernel<EPI_BNRELU,1><<<dim3(2, gyN), 256, 0, stream>>>(
        embO_bf, Wd_t, bd, hdec_bf, N, NHID2, NHID1, bn_g, bn_b, bn_m, bn_v);

    // ---- heads (fp32 final outputs) ----
    mfma_gemm_kernel<EPI_SIGMOID,0><<<dim3(4, gyN), 256, 0, stream>>>(
        hdec_bf, Wpi_t, bpi, pi, N, NHID1, NFEAT, nullptr, nullptr, nullptr, nullptr);
    mfma_gemm_kernel<EPI_SOFTPLUS,0><<<dim3(4, gyN), 256, 0, stream>>>(
        hdec_bf, Wv_t, bv, var_, N, NHID1, NFEAT, nullptr, nullptr, nullptr, nullptr);
    mfma_gemm_kernel<EPI_EXPCLIP,0><<<dim3(4, gyN), 256, 0, stream>>>(
        hdec_bf, Wmu_t, bmu, mean_, N, NHID1, NFEAT, nullptr, nullptr, nullptr, nullptr);
}

// Round 4
// 1097.633 us; speedup vs baseline: 2.3716x; 1.1288x over previous
//
#include <hip/hip_runtime.h>
#include <hip/hip_bf16.h>
#include <cstdint>
#include <cstddef>

#define NFEAT 512
#define NHID1 256
#define NHID2 64
#define ATTH  16

typedef __attribute__((ext_vector_type(8))) short short8v;           // 8 bf16 (4 VGPRs)
typedef __attribute__((ext_vector_type(8))) unsigned short ushort8v; // 16B load
typedef __attribute__((ext_vector_type(4))) float f32x4;             // mfma accumulator

enum { EPI_NONE=0, EPI_RELU=1, EPI_BNRELU=2, EPI_SIGMOID=3, EPI_SOFTPLUS=4, EPI_EXPCLIP=5 };

static __device__ __forceinline__ float bf2f(unsigned short u) {
    return __uint_as_float(((unsigned int)u) << 16);
}
static __device__ __forceinline__ unsigned short f2bf(float f) {
    __hip_bfloat16 h = __float2bfloat16(f);   // RNE
    return *reinterpret_cast<unsigned short*>(&h);
}

// ---------------- conversion kernels ----------------
__global__ __launch_bounds__(256) void convert_x_kernel(const float* __restrict__ in,
                                                        unsigned short* __restrict__ out, long n4) {
    long i = blockIdx.x * (long)blockDim.x + threadIdx.x;
    long stride = (long)gridDim.x * blockDim.x;
    for (; i < n4; i += stride) {
        float4 v = reinterpret_cast<const float4*>(in)[i];
        ushort4 o;
        o.x = f2bf(v.x); o.y = f2bf(v.y); o.z = f2bf(v.z); o.w = f2bf(v.w);
        reinterpret_cast<ushort4*>(out)[i] = o;
    }
}

struct WSpec { const float* W; unsigned short* Wt; int K, Nn; };
struct WPack { WSpec s[8]; };

// Wt[n][k] = bf16(W[k][n]) for all 8 weights in one launch; grid.y = weight id
__global__ __launch_bounds__(256) void convert_wt_all_kernel(WPack p) {
    WSpec sp = p.s[blockIdx.y];
    int total = sp.K * sp.Nn;
    for (int idx = blockIdx.x * 256 + threadIdx.x; idx < total; idx += gridDim.x * 256) {
        int n = idx / sp.K, k = idx % sp.K;
        sp.Wt[idx] = f2bf(sp.W[(size_t)k * sp.Nn + n]);
    }
}

// ---------------- bf16 MFMA GEMM: C = epi(A[M,K] @ Bt[Nn,K]^T + bias) ----------------
// 128x128 tile, 4 waves (2x2), 16x16x32 mfma, BK=32, global_load_lds width-16 staging.
// (unchanged — bit-identical numerics)
template<int EPI, int OUT_BF16>
__global__ __launch_bounds__(256) void mfma_gemm_kernel(
    const unsigned short* __restrict__ A, const unsigned short* __restrict__ Bt,
    const float* __restrict__ bias, void* __restrict__ Cout,
    int M, int K, int Nn,
    const float* __restrict__ bn_g, const float* __restrict__ bn_b,
    const float* __restrict__ bn_m, const float* __restrict__ bn_v)
{
    __shared__ unsigned short As[128 * 32];
    __shared__ unsigned short Bs[128 * 32];
    const int t = threadIdx.x;
    const int w = t >> 6, l = t & 63;
    const int wr = w >> 1, wc = w & 1;
    const int rowBase = blockIdx.y * 128, colBase = blockIdx.x * 128;

    f32x4 acc[4][4];
    #pragma unroll
    for (int m = 0; m < 4; ++m)
        #pragma unroll
        for (int n = 0; n < 4; ++n) acc[m][n] = (f32x4){0.f, 0.f, 0.f, 0.f};

    const int c0 = w * 2, c1 = w * 2 + 1;
    const int r0 = c0 * 16 + (l >> 2), r1 = c1 * 16 + (l >> 2);
    const int kid = (l & 3) * 8;
    int ar0 = rowBase + r0; if (ar0 >= M) ar0 = M - 1;
    int ar1 = rowBase + r1; if (ar1 >= M) ar1 = M - 1;
    int br0 = colBase + r0; if (br0 >= Nn) br0 = Nn - 1;
    int br1 = colBase + r1; if (br1 >= Nn) br1 = Nn - 1;
    const unsigned short* a0p = A + (size_t)ar0 * K + kid;
    const unsigned short* a1p = A + (size_t)ar1 * K + kid;
    const unsigned short* b0p = Bt + (size_t)br0 * K + kid;
    const unsigned short* b1p = Bt + (size_t)br1 * K + kid;

    const int frow = (l & 15), fk = (l >> 4) * 8;

    for (int k0 = 0; k0 < K; k0 += 32) {
        __builtin_amdgcn_global_load_lds(
            (const __attribute__((address_space(1))) void*)(a0p + k0),
            (__attribute__((address_space(3))) void*)(As + c0 * 512), 16, 0, 0);
        __builtin_amdgcn_global_load_lds(
            (const __attribute__((address_space(1))) void*)(a1p + k0),
            (__attribute__((address_space(3))) void*)(As + c1 * 512), 16, 0, 0);
        __builtin_amdgcn_global_load_lds(
            (const __attribute__((address_space(1))) void*)(b0p + k0),
            (__attribute__((address_space(3))) void*)(Bs + c0 * 512), 16, 0, 0);
        __builtin_amdgcn_global_load_lds(
            (const __attribute__((address_space(1))) void*)(b1p + k0),
            (__attribute__((address_space(3))) void*)(Bs + c1 * 512), 16, 0, 0);
        __syncthreads();

        short8v a[4], b[4];
        #pragma unroll
        for (int m = 0; m < 4; ++m)
            a[m] = *reinterpret_cast<const short8v*>(As + (wr * 64 + m * 16 + frow) * 32 + fk);
        #pragma unroll
        for (int n = 0; n < 4; ++n)
            b[n] = *reinterpret_cast<const short8v*>(Bs + (wc * 64 + n * 16 + frow) * 32 + fk);
        #pragma unroll
        for (int m = 0; m < 4; ++m)
            #pragma unroll
            for (int n = 0; n < 4; ++n)
                acc[m][n] = __builtin_amdgcn_mfma_f32_16x16x32_bf16(a[m], b[n], acc[m][n], 0, 0, 0);
        __syncthreads();
    }

    #pragma unroll
    for (int n = 0; n < 4; ++n) {
        int c = colBase + wc * 64 + n * 16 + (l & 15);
        if (c >= Nn) continue;
        float bia = bias ? bias[c] : 0.f;
        float g = 0.f, bb = 0.f, mm = 0.f, iv = 0.f;
        if (EPI == EPI_BNRELU) {
            g = bn_g[c]; bb = bn_b[c]; mm = bn_m[c];
            iv = rsqrtf(bn_v[c] + 1e-5f);
        }
        #pragma unroll
        for (int m = 0; m < 4; ++m) {
            #pragma unroll
            for (int j = 0; j < 4; ++j) {
                int r = rowBase + wr * 64 + m * 16 + (l >> 4) * 4 + j;
                if (r >= M) continue;
                float v = acc[m][n][j] + bia;
                if (EPI == EPI_RELU) {
                    v = fmaxf(v, 0.f);
                } else if (EPI == EPI_BNRELU) {
                    v = (v - mm) * iv * g + bb;
                    v = fmaxf(v, 0.f);
                } else if (EPI == EPI_SIGMOID) {
                    v = 1.f / (1.f + expf(-v));
                } else if (EPI == EPI_SOFTPLUS) {
                    float sp = (v > 20.f) ? v : log1pf(expf(v));
                    v = fminf(fmaxf(sp, 1e-4f), 1e4f);
                } else if (EPI == EPI_EXPCLIP) {
                    v = fminf(fmaxf(expf(v), 1e-5f), 1e6f);
                }
                if (OUT_BF16)
                    ((unsigned short*)Cout)[(size_t)r * Nn + c] = f2bf(v);
                else
                    ((float*)Cout)[(size_t)r * Nn + c] = v;
            }
        }
    }
}

// ---------------- combined CSR build (both graphs, rows 0..2N-1) ----------------
__global__ void hist2_kernel(const int* __restrict__ edst0, const int* __restrict__ edst1,
                             int* __restrict__ deg, int e, int nHalf) {
    int i = blockIdx.x * blockDim.x + threadIdx.x;
    if (i < 2 * e) {
        int d = (i < e) ? edst0[i] : (edst1[i - e] + nHalf);
        atomicAdd(&deg[d], 1);
    }
}

// multi-block scan: pass 1 — per-block exclusive scan + block sums
__global__ __launch_bounds__(1024) void scan_block_kernel(const int* __restrict__ deg,
                                                          int* __restrict__ excl,
                                                          int* __restrict__ bsum, int n) {
    __shared__ int buf[1024];
    int i = blockIdx.x * 1024 + (int)threadIdx.x;
    int v = (i < n) ? deg[i] : 0;
    buf[threadIdx.x] = v;
    __syncthreads();
    for (int off = 1; off < 1024; off <<= 1) {
        int tv = (threadIdx.x >= (unsigned)off) ? buf[threadIdx.x - off] : 0;
        __syncthreads();
        buf[threadIdx.x] += tv;
        __syncthreads();
    }
    if (i < n) excl[i] = buf[threadIdx.x] - v;
    if (threadIdx.x == 1023) bsum[blockIdx.x] = buf[1023];
}

// pass 2 — exclusive scan of block sums (single block, nb <= 1024)
__global__ __launch_bounds__(1024) void scan_tops_kernel(int* __restrict__ bsum, int nb) {
    __shared__ int buf[1024];
    int v = ((int)threadIdx.x < nb) ? bsum[threadIdx.x] : 0;
    buf[threadIdx.x] = v;
    __syncthreads();
    for (int off = 1; off < 1024; off <<= 1) {
        int tv = (threadIdx.x >= (unsigned)off) ? buf[threadIdx.x - off] : 0;
        __syncthreads();
        buf[threadIdx.x] += tv;
        __syncthreads();
    }
    if ((int)threadIdx.x < nb) bsum[threadIdx.x] = buf[threadIdx.x] - v;
}

// pass 3 — add block offsets, emit row_start + cursor + total
__global__ void scan_add_kernel(int* __restrict__ row_start, const int* __restrict__ bsum,
                                const int* __restrict__ deg, int* __restrict__ cursor, int n) {
    int i = blockIdx.x * blockDim.x + threadIdx.x;
    if (i < n) {
        int s = row_start[i] + bsum[i >> 10];
        row_start[i] = s;
        cursor[i] = s;
        if (i == n - 1) row_start[n] = s + deg[i];
    }
}

// ---- windowed XCD-local scatter ----
// window = blockIdx.x & 7 (~XCD id under round-robin dispatch). Each window
// streams the full edge list but scatters only dst in its id-range, so its
// stores land in a contiguous ~2E/8*4B slice of csr_src that stays in one
// XCD's L2 -> full-line writebacks instead of 64B-per-4B random HBM writes.
#define SC_EPT 8
__global__ __launch_bounds__(256) void scatter_win_kernel(
    const int* __restrict__ sadj, const int* __restrict__ fadj,
    int* __restrict__ cursor, int* __restrict__ csr_src,
    int e, int nHalf, int winSize)
{
    const int win = blockIdx.x & 7;
    const int chunk = blockIdx.x >> 3;
    const int lo = win * winSize, hi = lo + winSize;
    const int base = chunk * (256 * SC_EPT);
    const int e2 = 2 * e;
    #pragma unroll
    for (int r = 0; r < SC_EPT; ++r) {
        int i = base + r * 256 + (int)threadIdx.x;
        if (i >= e2) break;
        int src, d;
        if (i < e) { src = sadj[i];     d = sadj[e + i]; }
        else       { int j = i - e; src = fadj[j]; d = fadj[e + j] + nHalf; }
        if (d >= lo && d < hi) {
            int pos = atomicAdd(&cursor[d], 1);
            csr_src[pos] = src;   // raw source row 0..nHalf-1
        }
    }
}

// ---------------- gather aggregation (bf16 rows, fp32 accum) ----------------
// out[i,:] = bf16(relu(self[i,:] + sum_{s in row i} xin[base+s,:] + bias))
template<int F, bool SRC_OFFSET>
__global__ __launch_bounds__(256) void agg_combine_kernel(
    const unsigned short* __restrict__ xin, const int* __restrict__ row_start,
    const int* __restrict__ csr_src, const float* __restrict__ bias,
    unsigned short* __restrict__ out, int n2, int nHalf)
{
    constexpr int LPN = F / 8;                 // lanes per node, 8 bf16 (16B) each
    int node = blockIdx.x * (256 / LPN) + (int)threadIdx.x / LPN;
    int lane = (int)threadIdx.x % LPN;
    if (node >= n2) return;
    const int srcAdd  = (SRC_OFFSET && node >= nHalf) ? nHalf : 0;
    const int selfIdx = SRC_OFFSET ? node : (node >= nHalf ? node - nHalf : node);
    int beg = row_start[node], end = row_start[node + 1];
    float a[8];
    #pragma unroll
    for (int j = 0; j < 8; ++j) a[j] = 0.f;
    int e = beg;
    for (; e + 4 <= end; e += 4) {
        int s0 = csr_src[e] + srcAdd, s1 = csr_src[e+1] + srcAdd;
        int s2 = csr_src[e+2] + srcAdd, s3 = csr_src[e+3] + srcAdd;
        ushort8v v0 = *reinterpret_cast<const ushort8v*>(xin + (size_t)s0 * F + lane * 8);
        ushort8v v1 = *reinterpret_cast<const ushort8v*>(xin + (size_t)s1 * F + lane * 8);
        ushort8v v2 = *reinterpret_cast<const ushort8v*>(xin + (size_t)s2 * F + lane * 8);
        ushort8v v3 = *reinterpret_cast<const ushort8v*>(xin + (size_t)s3 * F + lane * 8);
        #pragma unroll
        for (int j = 0; j < 8; ++j)
            a[j] += bf2f(v0[j]) + bf2f(v1[j]) + bf2f(v2[j]) + bf2f(v3[j]);
    }
    for (; e < end; ++e) {
        int s = csr_src[e] + srcAdd;
        ushort8v v = *reinterpret_cast<const ushort8v*>(xin + (size_t)s * F + lane * 8);
        #pragma unroll
        for (int j = 0; j < 8; ++j) a[j] += bf2f(v[j]);
    }
    ushort8v sv = *reinterpret_cast<const ushort8v*>(xin + (size_t)selfIdx * F + lane * 8);
    ushort8v o;
    #pragma unroll
    for (int j = 0; j < 8; ++j)
        o[j] = f2bf(fmaxf(bf2f(sv[j]) + a[j] + bias[lane * 8 + j], 0.f));
    *reinterpret_cast<ushort8v*>(out + (size_t)node * F + lane * 8) = o;
}

// ---------------- fused spatial attention + mlp (16 nodes/block) ----------------
__global__ __launch_bounds__(256) void attn_mlp_kernel(
    const float* __restrict__ emb1, const float* __restrict__ emb2,
    const float* __restrict__ Wa1, const float* __restrict__ ba1,
    const float* __restrict__ Wa2, const float* __restrict__ Wmlp,
    const float* __restrict__ bmlp, float* __restrict__ out,
    unsigned short* __restrict__ out_bf, int n)
{
    __shared__ float sWa1[NHID2][ATTH];
    __shared__ float sba1[ATTH], sWa2[ATTH];
    __shared__ float sWmlp[NHID2][NHID2 + 1];
    __shared__ float sbmlp[NHID2];
    __shared__ float zs[4][3][NHID2 + 1];
    __shared__ float part[4][3][ATTH];
    __shared__ float sbeta[4][3];
    __shared__ float es[4][NHID2 + 1];

    int t = threadIdx.x;
    for (int idx = t; idx < NHID2 * ATTH; idx += 256) sWa1[idx / ATTH][idx % ATTH] = Wa1[idx];
    if (t < ATTH) { sba1[t] = ba1[t]; sWa2[t] = Wa2[t]; }
    for (int idx = t; idx < NHID2 * NHID2; idx += 256) sWmlp[idx / NHID2][idx % NHID2] = Wmlp[idx];
    if (t < NHID2) sbmlp[t] = bmlp[t];

    int w = t >> 6, lane = t & 63;

    for (int rep = 0; rep < 4; ++rep) {
        int node = blockIdx.x * 16 + rep * 4 + w;
        float z0 = 0.f, z2 = 0.f;
        if (node < n) {
            z0 = emb1[(size_t)node * NHID2 + lane];
            z2 = emb2[(size_t)node * NHID2 + lane];
        }
        zs[w][0][lane] = z0;
        zs[w][1][lane] = 0.5f * (z0 + z2);
        zs[w][2][lane] = z2;
        __syncthreads();

        if (t < 192) {
            int ww = t / 48, k = (t / 16) % 3, h = t % 16;
            float p = 0.f;
            #pragma unroll 8
            for (int i = 0; i < NHID2; ++i) p += zs[ww][k][i] * sWa1[i][h];
            part[ww][k][h] = tanhf(p + sba1[h]) * sWa2[h];
        }
        __syncthreads();
        if (t < 12) {
            int ww = t / 3, k = t % 3;
            float s = 0.f;
            #pragma unroll
            for (int h = 0; h < ATTH; ++h) s += part[ww][k][h];
            part[ww][k][0] = s;
        }
        __syncthreads();
        if (t < 4) {
            float w0 = part[t][0][0], w1 = part[t][1][0], w2 = part[t][2][0];
            float m = fmaxf(w0, fmaxf(w1, w2));
            float e0 = expf(w0 - m), e1 = expf(w1 - m), e2 = expf(w2 - m);
            float d = e0 + e1 + e2;
            sbeta[t][0] = e0 / d; sbeta[t][1] = e1 / d; sbeta[t][2] = e2 / d;
        }
        __syncthreads();
        es[w][lane] = sbeta[w][0] * zs[w][0][lane] + sbeta[w][1] * zs[w][1][lane]
                    + sbeta[w][2] * zs[w][2][lane];
        __syncthreads();
        if (node < n) {
            float v = sbmlp[lane];
            #pragma unroll 8
            for (int i = 0; i < NHID2; ++i) v = fmaf(es[w][i], sWmlp[i][lane], v);
            out[(size_t)node * NHID2 + lane] = v;
            out_bf[(size_t)node * NHID2 + lane] = f2bf(v);
        }
        __syncthreads();
    }
}

// ---------------- launcher ----------------
extern "C" void kernel_launch(void* const* d_in, const int* in_sizes, int n_in,
                              void* d_out, int out_size, void* d_ws, size_t ws_size,
                              hipStream_t stream) {
    const float* x    = (const float*)d_in[0];
    const int*   sadj = (const int*)d_in[1];
    const int*   fadj = (const int*)d_in[2];
    const int N = in_sizes[0] / NFEAT;
    const int E = in_sizes[1] / 2;
    const int N2 = 2 * N;
    const float* Wg1a = (const float*)d_in[3];
    const float* bg1a = (const float*)d_in[4];
    const float* Wg1b = (const float*)d_in[5];
    const float* bg1b = (const float*)d_in[6];
    const float* Wg2a = (const float*)d_in[7];
    const float* bg2a = (const float*)d_in[8];
    const float* Wg2b = (const float*)d_in[9];
    const float* bg2b = (const float*)d_in[10];
    const float* Wa1  = (const float*)d_in[11];
    const float* ba1  = (const float*)d_in[12];
    const float* Wa2  = (const float*)d_in[13];
    const float* Wmlp = (const float*)d_in[14];
    const float* bmlp = (const float*)d_in[15];
    const float* Wd   = (const float*)d_in[16];
    const float* bd   = (const float*)d_in[17];
    const float* bn_g = (const float*)d_in[18];
    const float* bn_b = (const float*)d_in[19];
    const float* bn_m = (const float*)d_in[20];
    const float* bn_v = (const float*)d_in[21];
    const float* Wpi  = (const float*)d_in[22];
    const float* bpi  = (const float*)d_in[23];
    const float* Wv   = (const float*)d_in[24];
    const float* bv   = (const float*)d_in[25];
    const float* Wmu  = (const float*)d_in[26];
    const float* bmu  = (const float*)d_in[27];

    float* out   = (float*)d_out;
    float* emb1  = out;                              // [N,64] (emb2 follows)
    float* embO  = out + 2 * (size_t)N * NHID2;      // [N,64]
    float* pi    = out + 3 * (size_t)N * NHID2;      // [N,512]
    float* var_  = pi + (size_t)N * NFEAT;           // [N,512]
    float* mean_ = var_ + (size_t)N * NFEAT;         // [N,512]

    // ---- workspace carve (256B aligned) ----
    char* wsb = (char*)d_ws;
    auto alloc = [&](size_t bytes) { char* p = wsb; wsb += (bytes + 255) & ~(size_t)255; return p; };
    unsigned short* xw_bf   = (unsigned short*)alloc((size_t)N  * NHID1 * 2);
    unsigned short* hw_bf   = (unsigned short*)alloc((size_t)N2 * NHID2 * 2);
    unsigned short* h3_bf   = (unsigned short*)alloc((size_t)N2 * NHID2 * 2);
    unsigned short* embO_bf = (unsigned short*)alloc((size_t)N  * NHID2 * 2);
    unsigned short* hdec_bf = (unsigned short*)alloc((size_t)N  * NHID1 * 2);
    unsigned short* Wg1a_t  = (unsigned short*)alloc((size_t)NFEAT * NHID1 * 2);
    unsigned short* Wg1b_t  = (unsigned short*)alloc((size_t)NHID1 * NHID1 * 2);
    unsigned short* Wg2a_t  = (unsigned short*)alloc((size_t)NHID1 * NHID2 * 2);
    unsigned short* Wg2b_t  = (unsigned short*)alloc((size_t)NHID2 * NHID2 * 2);
    unsigned short* Wd_t    = (unsigned short*)alloc((size_t)NHID2 * NHID1 * 2);
    unsigned short* Wpi_t   = (unsigned short*)alloc((size_t)NHID1 * NFEAT * 2);
    unsigned short* Wv_t    = (unsigned short*)alloc((size_t)NHID1 * NFEAT * 2);
    unsigned short* Wmu_t   = (unsigned short*)alloc((size_t)NHID1 * NFEAT * 2);
    int* deg       = (int*)alloc((size_t)N2 * 4);
    int* row_start = (int*)alloc((size_t)(N2 + 1) * 4);
    int* cursor    = (int*)alloc((size_t)N2 * 4);
    int* bsum      = (int*)alloc((size_t)1024 * 4);
    int* csr_src   = (int*)alloc((size_t)2 * E * 4);

    // big transient bf16 buffers live in not-yet-written output head segments
    unsigned short* x_bf  = (unsigned short*)mean_;  // [N,512]  bf16
    unsigned short* h1_bf = (unsigned short*)pi;     // [2N,256] bf16
    unsigned short* h_bf  = (unsigned short*)var_;   // [2N,256] bf16

    const int gyN  = (N + 127) / 128;
    const int gyN2 = (N2 + 127) / 128;
    const int nb   = (N2 + 1023) / 1024;

    // ---- conversions ----
    convert_x_kernel<<<2048, 256, 0, stream>>>(x, x_bf, (long)N * NFEAT / 4);
    WPack wp;
    wp.s[0] = {Wg1a, Wg1a_t, NFEAT, NHID1};
    wp.s[1] = {Wg1b, Wg1b_t, NHID1, NHID1};
    wp.s[2] = {Wg2a, Wg2a_t, NHID1, NHID2};
    wp.s[3] = {Wg2b, Wg2b_t, NHID2, NHID2};
    wp.s[4] = {Wd,   Wd_t,   NHID2, NHID1};
    wp.s[5] = {Wpi,  Wpi_t,  NHID1, NFEAT};
    wp.s[6] = {Wv,   Wv_t,   NHID1, NFEAT};
    wp.s[7] = {Wmu,  Wmu_t,  NHID1, NFEAT};
    convert_wt_all_kernel<<<dim3(64, 8), 256, 0, stream>>>(wp);

    // ---- combined CSR build (both graphs) ----
    hipMemsetAsync(deg, 0, (size_t)N2 * sizeof(int), stream);
    hist2_kernel<<<(2 * E + 255) / 256, 256, 0, stream>>>(sadj + E, fadj + E, deg, E, N);
    scan_block_kernel<<<nb, 1024, 0, stream>>>(deg, row_start, bsum, N2);
    scan_tops_kernel<<<1, 1024, 0, stream>>>(bsum, nb);
    scan_add_kernel<<<(N2 + 255) / 256, 256, 0, stream>>>(row_start, bsum, deg, cursor, N2);
    {
        const int chunks = (2 * E + 256 * SC_EPT - 1) / (256 * SC_EPT);
        const int winSize = (N2 + 7) / 8;
        scatter_win_kernel<<<chunks * 8, 256, 0, stream>>>(
            sadj, fadj, cursor, csr_src, E, N, winSize);
    }

    // ---- GIN, both graphs batched as M = 2N ----
    // xw = x @ Wg1a
    mfma_gemm_kernel<EPI_NONE,1><<<dim3(2, gyN), 256, 0, stream>>>(
        x_bf, Wg1a_t, nullptr, xw_bf, N, NFEAT, NHID1, nullptr, nullptr, nullptr, nullptr);
    // h1 = relu(xw_self + agg(xw) + bg1a)   [2N,256]
    agg_combine_kernel<NHID1,false><<<(N2 * (NHID1/8) + 255) / 256, 256, 0, stream>>>(
        xw_bf, row_start, csr_src, bg1a, h1_bf, N2, N);
    // h = relu(h1 @ Wg1b + bg1b)            [2N,256]
    mfma_gemm_kernel<EPI_RELU,1><<<dim3(2, gyN2), 256, 0, stream>>>(
        h1_bf, Wg1b_t, bg1b, h_bf, N2, NHID1, NHID1, nullptr, nullptr, nullptr, nullptr);
    // hw = h @ Wg2a                         [2N,64]
    mfma_gemm_kernel<EPI_NONE,1><<<dim3(1, gyN2), 256, 0, stream>>>(
        h_bf, Wg2a_t, nullptr, hw_bf, N2, NHID1, NHID2, nullptr, nullptr, nullptr, nullptr);
    // h3 = relu(hw_self + agg(hw) + bg2a)   [2N,64]
    agg_combine_kernel<NHID2,true><<<(N2 * (NHID2/8) + 255) / 256, 256, 0, stream>>>(
        hw_bf, row_start, csr_src, bg2a, h3_bf, N2, N);
    // emb1‖emb2 = h3 @ Wg2b + bg2b  (fp32, contiguous in d_out)
    mfma_gemm_kernel<EPI_NONE,0><<<dim3(1, gyN2), 256, 0, stream>>>(
        h3_bf, Wg2b_t, bg2b, emb1, N2, NHID2, NHID2, nullptr, nullptr, nullptr, nullptr);

    // ---- attention + mlp -> embO (fp32) + embO_bf ----
    attn_mlp_kernel<<<(N + 15) / 16, 256, 0, stream>>>(
        emb1, emb1 + (size_t)N * NHID2, Wa1, ba1, Wa2, Wmlp, bmlp, embO, embO_bf, N);

    // ---- decoder: hdec = relu(BN(embO @ Wd + bd)) ----
    mfma_gemm_kernel<EPI_BNRELU,1><<<dim3(2, gyN), 256, 0, stream>>>(
        embO_bf, Wd_t, bd, hdec_bf, N, NHID2, NHID1, bn_g, bn_b, bn_m, bn_v);

    // ---- heads (fp32 final outputs) ----
    mfma_gemm_kernel<EPI_SIGMOID,0><<<dim3(4, gyN), 256, 0, stream>>>(
        hdec_bf, Wpi_t, bpi, pi, N, NHID1, NFEAT, nullptr, nullptr, nullptr, nullptr);
    mfma_gemm_kernel<EPI_SOFTPLUS,0><<<dim3(4, gyN), 256, 0, stream>>>(
        hdec_bf, Wv_t, bv, var_, N, NHID1, NFEAT, nullptr, nullptr, nullptr, nullptr);
    mfma_gemm_kernel<EPI_EXPCLIP,0><<<dim3(4, gyN), 256, 0, stream>>>(
        hdec_bf, Wmu_t, bmu, mean_, N, NHID1, NFEAT, nullptr, nullptr, nullptr, nullptr);
}